// Round 6
// baseline (271.451 us; speedup 1.0000x reference)
//
#include <hip/hip_runtime.h>
#include <math.h>

#define HIDDEN 128
#define IDIM   50000
#define STEPS  100

typedef _Float16 half_t;
typedef _Float16 h2_t __attribute__((ext_vector_type(2)));

// ws layout (float offsets)
#define WS_E1H  0        // 256   e1 partials [2][128]
#define WS_CH   256      // 256   c  partials [2][128]
#define WS_M    512      // 16384 M = W_enc@W_dec (128x128)
#define WS_P    16896    // 49152 P = W_ih@M (384x128)
#define WS_Q    66048    // 384   q = W_ih@(c+b_enc)+b_ih
#define WS_IG1  66432    // 384   ig1 = W_ih@(e1+b_enc)+b_ih
#define WS_HT   66816    // 16384 H_T[i][k] (128x128, cols 0..99 used)

// d_out scratch layout (float offsets). All dead before k_decode writes.
#define SC_PART 0        // 500*16384 = 8.19M floats: M partials
#define SC_MP   9000000  // 10*16384 floats: stage-1 reduced partials

// Fused: blocks 0..499 = M-partial GEMM; blocks 500..755 = encoder dots.
__global__ __launch_bounds__(256, 2) void k_encgemm(const float* __restrict__ W_enc,
    const float* __restrict__ W_dec, const float* __restrict__ x0,
    const float* __restrict__ b_dec, float* __restrict__ ws,
    float* __restrict__ scratch)
{
  __shared__ __align__(16) float smem[1024];
  const int t = threadIdx.x;

  if (blockIdx.x < 500){
    // ---- M partials: K-chunk of 100; 128x128 tile, 8x8 micro-tile ----
    float (*As)[128] = (float(*)[128])smem;          // [4][128]
    float (*Bs)[128] = (float(*)[128])(smem + 512);  // [4][128]
    const int tx = t & 15, ty = t >> 4;
    const int d0 = blockIdx.x * 100;
    const int u  = t - 128, ukk = u >> 5, ug = u & 31;
    float acc[8][8];
    #pragma unroll
    for (int p = 0; p < 8; p++)
      #pragma unroll
      for (int q = 0; q < 8; q++) acc[p][q] = 0.f;

    float4 stage;
    if (t < 128) stage = *(const float4*)(W_enc + (size_t)t*IDIM + d0);
    else         stage = *(const float4*)(W_dec + (size_t)(d0+ukk)*HIDDEN + ug*4);

    for (int k0 = 0; k0 < 100; k0 += 4){
      if (t < 128){
        As[0][t] = stage.x; As[1][t] = stage.y; As[2][t] = stage.z; As[3][t] = stage.w;
      } else {
        *(float4*)&Bs[ukk][ug*4] = stage;
      }
      __syncthreads();
      if (k0 + 4 < 100){
        if (t < 128) stage = *(const float4*)(W_enc + (size_t)t*IDIM + d0 + k0 + 4);
        else         stage = *(const float4*)(W_dec + (size_t)(d0+k0+4+ukk)*HIDDEN + ug*4);
      }
      #pragma unroll
      for (int kk = 0; kk < 4; kk++){
        float4 alo = *(const float4*)&As[kk][ty*8];
        float4 ahi = *(const float4*)&As[kk][ty*8+4];
        float4 blo = *(const float4*)&Bs[kk][tx*8];
        float4 bhi = *(const float4*)&Bs[kk][tx*8+4];
        float a[8] = {alo.x,alo.y,alo.z,alo.w,ahi.x,ahi.y,ahi.z,ahi.w};
        float b[8] = {blo.x,blo.y,blo.z,blo.w,bhi.x,bhi.y,bhi.z,bhi.w};
        #pragma unroll
        for (int p = 0; p < 8; p++)
          #pragma unroll
          for (int q = 0; q < 8; q++) acc[p][q] += a[p]*b[q];
      }
      __syncthreads();
    }
    float* outp = scratch + (size_t)blockIdx.x * 16384;
    #pragma unroll
    for (int p = 0; p < 8; p++){
      #pragma unroll
      for (int q = 0; q < 8; q += 4){
        *(float4*)&outp[(ty*8+p)*128 + tx*8 + q] =
          make_float4(acc[p][q], acc[p][q+1], acc[p][q+2], acc[p][q+3]);
      }
    }
  } else {
    // ---- encoder: e1p/cp block partials ----
    const int bid  = blockIdx.x - 500;
    const int r    = bid >> 1;
    const int half = bid & 1;
    float* r0 = smem;         // [256]
    float* r1 = smem + 256;   // [256]
    const float4* wr = (const float4*)(W_enc + (size_t)r*IDIM + half*25000);
    const float4* xv = (const float4*)(x0   + half*25000);
    const float4* bv = (const float4*)(b_dec + half*25000);
    float s0 = 0.f, s1 = 0.f;
    for (int i = t; i < 6250; i += 256){
      float4 w = wr[i]; float4 a = xv[i]; float4 b = bv[i];
      s0 += w.x*a.x + w.y*a.y + w.z*a.z + w.w*a.w;
      s1 += w.x*b.x + w.y*b.y + w.z*b.z + w.w*b.w;
    }
    r0[t] = s0; r1[t] = s1;
    __syncthreads();
    for (int off = 128; off > 0; off >>= 1){
      if (t < off){ r0[t] += r0[t+off]; r1[t] += r1[t+off]; }
      __syncthreads();
    }
    if (t == 0){
      ws[WS_E1H + half*128 + r] = r0[0];
      ws[WS_CH  + half*128 + r] = r1[0];
    }
  }
}

// Stage 1: 640 blocks; block (chunk, g) sums partials g*50..g*50+49.
__global__ __launch_bounds__(256) void k_reduce1(const float* __restrict__ scratch,
    float* __restrict__ Mp)
{
  const int g     = blockIdx.x % 10;
  const int chunk = blockIdx.x / 10;
  const int idx   = chunk * 256 + threadIdx.x;
  const float* base = scratch + (size_t)(g*50) * 16384 + idx;
  float s[10];
  #pragma unroll
  for (int uu = 0; uu < 10; uu++) s[uu] = 0.f;
  for (int p = 0; p < 50; p += 10){
    #pragma unroll
    for (int uu = 0; uu < 10; uu++)
      s[uu] += base[(size_t)(p+uu)*16384];
  }
  float t0 = (s[0]+s[1]) + (s[2]+s[3]);
  float t1 = (s[4]+s[5]) + (s[6]+s[7]);
  Mp[(size_t)g*16384 + idx] = t0 + t1 + (s[8]+s[9]);
}

// Stage 2: 64 blocks, sum 10 -> M.
__global__ __launch_bounds__(256) void k_reduce2(const float* __restrict__ Mp,
    float* __restrict__ Mout)
{
  const int idx = blockIdx.x * 256 + threadIdx.x;
  float s = 0.f;
  #pragma unroll
  for (int g = 0; g < 10; g++) s += Mp[(size_t)g*16384 + idx];
  Mout[idx] = s;
}

// P[r,:] = W_ih[r,:]@M ; q[r] ; ig1[r]. 384 blocks x 128 threads.
__global__ __launch_bounds__(128) void k_smallP(const float* __restrict__ W_ih,
    const float* __restrict__ b_ih, const float* __restrict__ b_enc,
    const float* __restrict__ ws, const float* __restrict__ M,
    float* __restrict__ P, float* __restrict__ q, float* __restrict__ ig1)
{
  const int r = blockIdx.x, j = threadIdx.x;
  const float* wr = W_ih + (size_t)r * HIDDEN;
  float acc = 0.f;
  #pragma unroll 8
  for (int k = 0; k < HIDDEN; k++) acc += wr[k] * M[k*HIDDEN + j];
  P[(size_t)r*HIDDEN + j] = acc;
  const float wj = wr[j];
  float cj  = ws[WS_CH  + j] + ws[WS_CH  + 128 + j];
  float e1j = ws[WS_E1H + j] + ws[WS_E1H + 128 + j];
  float t0 = wj * (cj  + b_enc[j]);
  float t1 = wj * (e1j + b_enc[j]);
  __shared__ float r0[128], r1[128];
  r0[j] = t0; r1[j] = t1;
  __syncthreads();
  for (int off = 64; off > 0; off >>= 1){
    if (j < off){ r0[j] += r0[j+off]; r1[j] += r1[j+off]; }
    __syncthreads();
  }
  if (j == 0){
    q[r]   = r0[0] + b_ih[r];
    ig1[r] = r1[0] + b_ih[r];
  }
}

// ---- fast transcendentals ----
__device__ __forceinline__ float fexp2_(float x){ return __builtin_amdgcn_exp2f(x); }
__device__ __forceinline__ float frcp_(float x){ return __builtin_amdgcn_rcpf(x); }
__device__ __forceinline__ float fsig_(float x){
  return frcp_(1.f + fexp2_(x * -1.44269504f));
}
__device__ __forceinline__ float ftanh_(float x){
  return 1.f - 2.f * frcp_(fexp2_(x * 2.88539008f) + 1.f);
}
// quad swaps: lane ^1 (0xB1 = [1,0,3,2]) and lane ^2 (0x4E = [2,3,0,1])
__device__ __forceinline__ float dppx1_(float x){
  return __builtin_bit_cast(float,
      __builtin_amdgcn_mov_dpp(__builtin_bit_cast(int, x), 0xB1, 0xF, 0xF, true));
}
__device__ __forceinline__ float dppx2_(float x){
  return __builtin_bit_cast(float,
      __builtin_amdgcn_mov_dpp(__builtin_bit_cast(int, x), 0x4E, 0xF, 0xF, true));
}

// Sequential recurrence. R6: 512 threads (8 waves, 2/SIMD), 4-way k-split.
// R5 post-mortem: VALUBusy showed v_dot2_f32_f16 is ~4-cyc issue; per-step
// 1730 cyc = ~830 VALU issue + ~900 UNHIDDEN latency (LDS round-trip, serial
// transcendental chain, barrier) because 1 wave/SIMD had nothing to overlap.
// Now thread p of quad e computes all 6 gate rows over k in [32p,32p+32):
// per-SIMD issue unchanged (2 waves x 96 fdot2), but the second wave's fdot2
// stream hides the first's nonlin/LDS/barrier tail. Quad reduce: DPP ^1 + ^2
// (both intra-quad, no LDS). ~150 VGPR -> clean 2 waves/EU.
__global__
__attribute__((amdgpu_flat_work_group_size(512, 512), amdgpu_waves_per_eu(2, 2)))
void k_recur(const float* __restrict__ P,
    const float* __restrict__ W_hh, const float* __restrict__ q,
    const float* __restrict__ b_n, const float* __restrict__ ig1,
    float* __restrict__ H_T)
{
  const int t = threadIdx.x;
  const int e = t >> 2;          // hidden element 0..127
  const int p = t & 3;           // k-quarter

  const float* rP0 = P    + (size_t)e         * HIDDEN + p*32;
  const float* rP1 = P    + (size_t)(128 + e) * HIDDEN + p*32;
  const float* rP2 = P    + (size_t)(256 + e) * HIDDEN + p*32;
  const float* rH0 = W_hh + (size_t)e         * HIDDEN + p*32;
  const float* rH1 = W_hh + (size_t)(128 + e) * HIDDEN + p*32;
  const float* rH2 = W_hh + (size_t)(256 + e) * HIDDEN + p*32;

  // q biases carried by the p=0 partials only (added once per full sum)
  const float qa = p ? 0.f : q[e];
  const float qb = p ? 0.f : q[128 + e];
  const float qc = p ? 0.f : q[256 + e];

  h2_t wP0[16], wP1[16], wP2[16], wH0[16], wH1[16], wH2[16];
#define LOADROW(DST, SRC)                                                     \
  { const float4* f = (const float4*)(SRC);                                   \
    _Pragma("unroll")                                                         \
    for (int j = 0; j < 8; j++){                                              \
      float4 v = f[j];                                                        \
      h2_t w;                                                                 \
      w.x=(half_t)v.x; w.y=(half_t)v.y; DST[2*j]   = w;                       \
      w.x=(half_t)v.z; w.y=(half_t)v.w; DST[2*j+1] = w;                       \
    } }
  LOADROW(wP0, rP0); LOADROW(wP1, rP1); LOADROW(wP2, rP2);
  LOADROW(wH0, rH0); LOADROW(wH1, rH1); LOADROW(wH2, rH2);
#undef LOADROW

  __shared__ __align__(16) half_t h16[2][HIDDEN];   // double-buffered broadcast
  __shared__ float Hs[128 * 101];                   // h history, padded rows

  const float bn = b_n[e];
  float h;
  {
    float reset = fsig_(ig1[e]);
    float inp   = fsig_(ig1[128 + e]);
    float nw    = ftanh_(ig1[256 + e] + reset * bn);
    h = nw - inp * nw;
  }
  if (p == 0) h16[0][e] = (half_t)h;
  else if (p == 1) Hs[e * 101] = h;
  __syncthreads();

  // step KK: reads own k-quarter (64B, 4 x b128) of h16[RD], 6 quarter-dots,
  // quad-sums via DPP ^1+^2, nonlinearity redundantly in all 4 lanes.
#define RSTEP(KK, RD, WR)                                                     \
  {                                                                           \
    const uint4* hq = ((const uint4*)(h16[RD])) + p*4;                        \
    float a0 = qa,  a1 = 0.f;   /* P row e      -> ig_r partial */            \
    float b0 = qb,  b1 = 0.f;   /* P row 128+e  -> ig_i partial */            \
    float c0 = qc,  c1 = 0.f;   /* P row 256+e  -> ig_n partial */            \
    float d0 = 0.f, d1 = 0.f;   /* W row e      -> hg_r partial */            \
    float g0 = 0.f, g1 = 0.f;   /* W row 128+e  -> hg_i partial */            \
    float f0 = 0.f, f1 = 0.f;   /* W row 256+e  -> hg_n partial */            \
    _Pragma("unroll")                                                         \
    for (int jj = 0; jj < 4; jj++){                                           \
      uint4 hb = hq[jj];                                                      \
      h2_t hx = __builtin_bit_cast(h2_t, hb.x);                               \
      h2_t hy = __builtin_bit_cast(h2_t, hb.y);                               \
      h2_t hz = __builtin_bit_cast(h2_t, hb.z);                               \
      h2_t hw = __builtin_bit_cast(h2_t, hb.w);                               \
      a0 = __builtin_amdgcn_fdot2(wP0[4*jj+0], hx, a0, false);                \
      a1 = __builtin_amdgcn_fdot2(wP0[4*jj+1], hy, a1, false);                \
      a0 = __builtin_amdgcn_fdot2(wP0[4*jj+2], hz, a0, false);                \
      a1 = __builtin_amdgcn_fdot2(wP0[4*jj+3], hw, a1, false);                \
      b0 = __builtin_amdgcn_fdot2(wP1[4*jj+0], hx, b0, false);                \
      b1 = __builtin_amdgcn_fdot2(wP1[4*jj+1], hy, b1, false);                \
      b0 = __builtin_amdgcn_fdot2(wP1[4*jj+2], hz, b0, false);                \
      b1 = __builtin_amdgcn_fdot2(wP1[4*jj+3], hw, b1, false);                \
      c0 = __builtin_amdgcn_fdot2(wP2[4*jj+0], hx, c0, false);                \
      c1 = __builtin_amdgcn_fdot2(wP2[4*jj+1], hy, c1, false);                \
      c0 = __builtin_amdgcn_fdot2(wP2[4*jj+2], hz, c0, false);                \
      c1 = __builtin_amdgcn_fdot2(wP2[4*jj+3], hw, c1, false);                \
      d0 = __builtin_amdgcn_fdot2(wH0[4*jj+0], hx, d0, false);                \
      d1 = __builtin_amdgcn_fdot2(wH0[4*jj+1], hy, d1, false);                \
      d0 = __builtin_amdgcn_fdot2(wH0[4*jj+2], hz, d0, false);                \
      d1 = __builtin_amdgcn_fdot2(wH0[4*jj+3], hw, d1, false);                \
      g0 = __builtin_amdgcn_fdot2(wH1[4*jj+0], hx, g0, false);                \
      g1 = __builtin_amdgcn_fdot2(wH1[4*jj+1], hy, g1, false);                \
      g0 = __builtin_amdgcn_fdot2(wH1[4*jj+2], hz, g0, false);                \
      g1 = __builtin_amdgcn_fdot2(wH1[4*jj+3], hw, g1, false);                \
      f0 = __builtin_amdgcn_fdot2(wH2[4*jj+0], hx, f0, false);                \
      f1 = __builtin_amdgcn_fdot2(wH2[4*jj+1], hy, f1, false);                \
      f0 = __builtin_amdgcn_fdot2(wH2[4*jj+2], hz, f0, false);                \
      f1 = __builtin_amdgcn_fdot2(wH2[4*jj+3], hw, f1, false);                \
    }                                                                         \
    float A = a0 + a1, B = b0 + b1, C = c0 + c1;                              \
    float D = d0 + d1, G = g0 + g1, F = f0 + f1;                              \
    A += dppx1_(A); B += dppx1_(B); C += dppx1_(C);                           \
    D += dppx1_(D); G += dppx1_(G); F += dppx1_(F);                           \
    A += dppx2_(A); B += dppx2_(B); C += dppx2_(C);                           \
    D += dppx2_(D); G += dppx2_(G); F += dppx2_(F);                           \
    float rs = fsig_(A + D);                                                  \
    float ip = fsig_(B + G);                                                  \
    float nw = ftanh_(C + rs * (F + bn));                                     \
    h = nw + ip * (h - nw);                                                   \
    if (p == 0) h16[WR][e] = (half_t)h;                                       \
    else if (p == 1) Hs[e * 101 + (KK)] = h;                                  \
    __syncthreads();                                                          \
  }

  for (int k = 1; k < STEPS - 1; k += 2){
    RSTEP(k,     0, 1);
    RSTEP(k + 1, 1, 0);
  }
  RSTEP(STEPS - 1, 0, 1); // k = 99
#undef RSTEP

  // Coalesced dump: H_T[e*128 + k] = Hs[e][k] (k<100), 0 otherwise.
  for (int i = 0; i < 32; i++){
    int f = i * 512 + t;
    int ee = f >> 7, kk = f & 127;
    H_T[f] = (kk < STEPS) ? Hs[ee * 101 + kk] : 0.f;
  }
}

// X[k][d] = W_dec[d,:]@h_k + b_dec[d].
// W_dec staged through LDS via fully-coalesced contiguous loads; H read
// directly from global with 16-lane-uniform broadcast addresses (L2-hot).
__global__ __launch_bounds__(256, 4) void k_decode(const float* __restrict__ W_dec,
    const float* __restrict__ b_dec, const float* __restrict__ H_T,
    float* __restrict__ out)
{
  __shared__ __align__(16) float Ws[64][132];   // 33792 B, rows 528B (16B-mult)
  const int t  = threadIdx.x;
  const int tx = t & 15, ty = t >> 4;
  const int d0 = blockIdx.x * 64;

  #pragma unroll
  for (int i = 0; i < 8; i++){
    int f4 = i * 256 + t;
    int rl = f4 >> 5;            // local row 0..63
    int cl = (f4 & 31) * 4;      // col 0..124
    int rg = d0 + rl;
    float4 v = *(const float4*)&W_dec[(size_t)((rg < IDIM) ? rg : 0)*HIDDEN + cl];
    *(float4*)&Ws[rl][cl] = v;
  }
  __syncthreads();

  float acc[4][8];
  #pragma unroll
  for (int p = 0; p < 4; p++)
    #pragma unroll
    for (int q = 0; q < 8; q++) acc[p][q] = 0.f;

  for (int j0 = 0; j0 < HIDDEN; j0 += 4){
    float4 a0 = *(const float4*)&Ws[tx     ][j0];
    float4 a1 = *(const float4*)&Ws[tx + 16][j0];
    float4 a2 = *(const float4*)&Ws[tx + 32][j0];
    float4 a3 = *(const float4*)&Ws[tx + 48][j0];
    #pragma unroll
    for (int jj = 0; jj < 4; jj++){
      const float* hrow = H_T + (size_t)(j0 + jj) * HIDDEN + ty * 8;
      float4 b0 = *(const float4*)hrow;        // lane-uniform across tx: broadcast
      float4 b1 = *(const float4*)(hrow + 4);
      float e0 = (jj==0)?a0.x:(jj==1)?a0.y:(jj==2)?a0.z:a0.w;
      float e1 = (jj==0)?a1.x:(jj==1)?a1.y:(jj==2)?a1.z:a1.w;
      float e2 = (jj==0)?a2.x:(jj==1)?a2.y:(jj==2)?a2.z:a2.w;
      float e3 = (jj==0)?a3.x:(jj==1)?a3.y:(jj==2)?a3.z:a3.w;
      acc[0][0]+=e0*b0.x; acc[0][1]+=e0*b0.y; acc[0][2]+=e0*b0.z; acc[0][3]+=e0*b0.w;
      acc[0][4]+=e0*b1.x; acc[0][5]+=e0*b1.y; acc[0][6]+=e0*b1.z; acc[0][7]+=e0*b1.w;
      acc[1][0]+=e1*b0.x; acc[1][1]+=e1*b0.y; acc[1][2]+=e1*b0.z; acc[1][3]+=e1*b0.w;
      acc[1][4]+=e1*b1.x; acc[1][5]+=e1*b1.y; acc[1][6]+=e1*b1.z; acc[1][7]+=e1*b1.w;
      acc[2][0]+=e2*b0.x; acc[2][1]+=e2*b0.y; acc[2][2]+=e2*b0.z; acc[2][3]+=e2*b0.w;
      acc[2][4]+=e2*b1.x; acc[2][5]+=e2*b1.y; acc[2][6]+=e2*b1.z; acc[2][7]+=e2*b1.w;
      acc[3][0]+=e3*b0.x; acc[3][1]+=e3*b0.y; acc[3][2]+=e3*b0.z; acc[3][3]+=e3*b0.w;
      acc[3][4]+=e3*b1.x; acc[3][5]+=e3*b1.y; acc[3][6]+=e3*b1.z; acc[3][7]+=e3*b1.w;
    }
  }

  bool dv[4]; float bd[4];
  #pragma unroll
  for (int p = 0; p < 4; p++){
    int d = d0 + tx + 16*p;
    dv[p] = (d < IDIM);
    bd[p] = dv[p] ? b_dec[d] : 0.f;
  }
  const size_t SO = (size_t)STEPS * IDIM;  // 5,000,000
  #pragma unroll
  for (int qq = 0; qq < 8; qq++){
    int k = ty*8 + qq;
    if (k < STEPS){
      size_t o = (size_t)k * IDIM + d0 + tx;
      #pragma unroll
      for (int p = 0; p < 4; p++){
        if (dv[p]){
          float v = acc[p][qq] + bd[p];
          out[o + 16*p]          = v;    // samples
          out[o + 16*p + SO]     = v;    // means
          out[o + 16*p + 2*SO]   = 0.f;  // sigmas
        }
      }
    }
  }
}

extern "C" void kernel_launch(void* const* d_in, const int* in_sizes, int n_in,
                              void* d_out, int out_size, void* d_ws, size_t ws_size,
                              hipStream_t stream) {
  const float* x0    = (const float*)d_in[0];
  const float* W_enc = (const float*)d_in[1];
  const float* b_enc = (const float*)d_in[2];
  const float* W_ih  = (const float*)d_in[3];
  const float* W_hh  = (const float*)d_in[4];
  const float* b_ih  = (const float*)d_in[5];
  const float* b_n   = (const float*)d_in[6];
  const float* W_dec = (const float*)d_in[7];
  const float* b_dec = (const float*)d_in[8];
  (void)in_sizes; (void)n_in; (void)out_size; (void)ws_size;

  float* out = (float*)d_out;
  float* ws  = (float*)d_ws;
  float* M   = ws + WS_M;
  float* P   = ws + WS_P;
  float* q   = ws + WS_Q;
  float* ig1 = ws + WS_IG1;
  float* H_T = ws + WS_HT;
  float* scratch = out + SC_PART;  // 32 MB of d_out, dead until k_decode
  float* Mp      = out + SC_MP;    // 640 KB of d_out, ditto

  hipLaunchKernelGGL(k_encgemm, dim3(756), dim3(256), 0, stream, W_enc, W_dec, x0, b_dec, ws, scratch);
  hipLaunchKernelGGL(k_reduce1, dim3(640), dim3(256), 0, stream, scratch, Mp);
  hipLaunchKernelGGL(k_reduce2, dim3(64),  dim3(256), 0, stream, Mp, M);
  hipLaunchKernelGGL(k_smallP,  dim3(384), dim3(128), 0, stream, W_ih, b_ih, b_enc, ws, M, P, q, ig1);
  hipLaunchKernelGGL(k_recur,   dim3(1),   dim3(512), 0, stream, P, W_hh, q, b_n, ig1, H_T);
  hipLaunchKernelGGL(k_decode,  dim3(782), dim3(256), 0, stream, W_dec, b_dec, H_T, out);
}

// Round 7
// 251.736 us; speedup vs baseline: 1.0783x; 1.0783x over previous
//
#include <hip/hip_runtime.h>
#include <math.h>

#define HIDDEN 128
#define IDIM   50000
#define STEPS  100

typedef _Float16 half_t;
typedef _Float16 h2_t __attribute__((ext_vector_type(2)));

// ws layout (float offsets)
#define WS_E1H  0        // 256   e1 partials [2][128]
#define WS_CH   256      // 256   c  partials [2][128]
#define WS_M    512      // 16384 M = W_enc@W_dec (128x128)
#define WS_P    16896    // 49152 P = W_ih@M (384x128)
#define WS_Q    66048    // 384   q = W_ih@(c+b_enc)+b_ih
#define WS_IG1  66432    // 384   ig1 = W_ih@(e1+b_enc)+b_ih
#define WS_HT   66816    // 16384 H_T[i][k] (128x128, cols 0..99 used)

// d_out scratch layout (float offsets). All dead before k_decode writes.
#define SC_PART 0        // 500*16384 = 8.19M floats: M partials
#define SC_MP   9000000  // 10*16384 floats: stage-1 reduced partials

// Fused: blocks 0..499 = M-partial GEMM; blocks 500..755 = encoder dots.
__global__ __launch_bounds__(256, 2) void k_encgemm(const float* __restrict__ W_enc,
    const float* __restrict__ W_dec, const float* __restrict__ x0,
    const float* __restrict__ b_dec, float* __restrict__ ws,
    float* __restrict__ scratch)
{
  __shared__ __align__(16) float smem[1024];
  const int t = threadIdx.x;

  if (blockIdx.x < 500){
    // ---- M partials: K-chunk of 100; 128x128 tile, 8x8 micro-tile ----
    float (*As)[128] = (float(*)[128])smem;          // [4][128]
    float (*Bs)[128] = (float(*)[128])(smem + 512);  // [4][128]
    const int tx = t & 15, ty = t >> 4;
    const int d0 = blockIdx.x * 100;
    const int u  = t - 128, ukk = u >> 5, ug = u & 31;
    float acc[8][8];
    #pragma unroll
    for (int p = 0; p < 8; p++)
      #pragma unroll
      for (int q = 0; q < 8; q++) acc[p][q] = 0.f;

    float4 stage;
    if (t < 128) stage = *(const float4*)(W_enc + (size_t)t*IDIM + d0);
    else         stage = *(const float4*)(W_dec + (size_t)(d0+ukk)*HIDDEN + ug*4);

    for (int k0 = 0; k0 < 100; k0 += 4){
      if (t < 128){
        As[0][t] = stage.x; As[1][t] = stage.y; As[2][t] = stage.z; As[3][t] = stage.w;
      } else {
        *(float4*)&Bs[ukk][ug*4] = stage;
      }
      __syncthreads();
      if (k0 + 4 < 100){
        if (t < 128) stage = *(const float4*)(W_enc + (size_t)t*IDIM + d0 + k0 + 4);
        else         stage = *(const float4*)(W_dec + (size_t)(d0+k0+4+ukk)*HIDDEN + ug*4);
      }
      #pragma unroll
      for (int kk = 0; kk < 4; kk++){
        float4 alo = *(const float4*)&As[kk][ty*8];
        float4 ahi = *(const float4*)&As[kk][ty*8+4];
        float4 blo = *(const float4*)&Bs[kk][tx*8];
        float4 bhi = *(const float4*)&Bs[kk][tx*8+4];
        float a[8] = {alo.x,alo.y,alo.z,alo.w,ahi.x,ahi.y,ahi.z,ahi.w};
        float b[8] = {blo.x,blo.y,blo.z,blo.w,bhi.x,bhi.y,bhi.z,bhi.w};
        #pragma unroll
        for (int p = 0; p < 8; p++)
          #pragma unroll
          for (int q = 0; q < 8; q++) acc[p][q] += a[p]*b[q];
      }
      __syncthreads();
    }
    float* outp = scratch + (size_t)blockIdx.x * 16384;
    #pragma unroll
    for (int p = 0; p < 8; p++){
      #pragma unroll
      for (int q = 0; q < 8; q += 4){
        *(float4*)&outp[(ty*8+p)*128 + tx*8 + q] =
          make_float4(acc[p][q], acc[p][q+1], acc[p][q+2], acc[p][q+3]);
      }
    }
  } else {
    // ---- encoder: e1p/cp block partials ----
    const int bid  = blockIdx.x - 500;
    const int r    = bid >> 1;
    const int half = bid & 1;
    float* r0 = smem;         // [256]
    float* r1 = smem + 256;   // [256]
    const float4* wr = (const float4*)(W_enc + (size_t)r*IDIM + half*25000);
    const float4* xv = (const float4*)(x0   + half*25000);
    const float4* bv = (const float4*)(b_dec + half*25000);
    float s0 = 0.f, s1 = 0.f;
    for (int i = t; i < 6250; i += 256){
      float4 w = wr[i]; float4 a = xv[i]; float4 b = bv[i];
      s0 += w.x*a.x + w.y*a.y + w.z*a.z + w.w*a.w;
      s1 += w.x*b.x + w.y*b.y + w.z*b.z + w.w*b.w;
    }
    r0[t] = s0; r1[t] = s1;
    __syncthreads();
    for (int off = 128; off > 0; off >>= 1){
      if (t < off){ r0[t] += r0[t+off]; r1[t] += r1[t+off]; }
      __syncthreads();
    }
    if (t == 0){
      ws[WS_E1H + half*128 + r] = r0[0];
      ws[WS_CH  + half*128 + r] = r1[0];
    }
  }
}

// Stage 1: 640 blocks; block (chunk, g) sums partials g*50..g*50+49.
__global__ __launch_bounds__(256) void k_reduce1(const float* __restrict__ scratch,
    float* __restrict__ Mp)
{
  const int g     = blockIdx.x % 10;
  const int chunk = blockIdx.x / 10;
  const int idx   = chunk * 256 + threadIdx.x;
  const float* base = scratch + (size_t)(g*50) * 16384 + idx;
  float s[10];
  #pragma unroll
  for (int uu = 0; uu < 10; uu++) s[uu] = 0.f;
  for (int p = 0; p < 50; p += 10){
    #pragma unroll
    for (int uu = 0; uu < 10; uu++)
      s[uu] += base[(size_t)(p+uu)*16384];
  }
  float t0 = (s[0]+s[1]) + (s[2]+s[3]);
  float t1 = (s[4]+s[5]) + (s[6]+s[7]);
  Mp[(size_t)g*16384 + idx] = t0 + t1 + (s[8]+s[9]);
}

// Stage 2: 64 blocks, sum 10 -> M.
__global__ __launch_bounds__(256) void k_reduce2(const float* __restrict__ Mp,
    float* __restrict__ Mout)
{
  const int idx = blockIdx.x * 256 + threadIdx.x;
  float s = 0.f;
  #pragma unroll
  for (int g = 0; g < 10; g++) s += Mp[(size_t)g*16384 + idx];
  Mout[idx] = s;
}

// P[r,:] = W_ih[r,:]@M ; q[r] ; ig1[r]. 384 blocks x 128 threads.
__global__ __launch_bounds__(128) void k_smallP(const float* __restrict__ W_ih,
    const float* __restrict__ b_ih, const float* __restrict__ b_enc,
    const float* __restrict__ ws, const float* __restrict__ M,
    float* __restrict__ P, float* __restrict__ q, float* __restrict__ ig1)
{
  const int r = blockIdx.x, j = threadIdx.x;
  const float* wr = W_ih + (size_t)r * HIDDEN;
  float acc = 0.f;
  #pragma unroll 8
  for (int k = 0; k < HIDDEN; k++) acc += wr[k] * M[k*HIDDEN + j];
  P[(size_t)r*HIDDEN + j] = acc;
  const float wj = wr[j];
  float cj  = ws[WS_CH  + j] + ws[WS_CH  + 128 + j];
  float e1j = ws[WS_E1H + j] + ws[WS_E1H + 128 + j];
  float t0 = wj * (cj  + b_enc[j]);
  float t1 = wj * (e1j + b_enc[j]);
  __shared__ float r0[128], r1[128];
  r0[j] = t0; r1[j] = t1;
  __syncthreads();
  for (int off = 64; off > 0; off >>= 1){
    if (j < off){ r0[j] += r0[j+off]; r1[j] += r1[j+off]; }
    __syncthreads();
  }
  if (j == 0){
    q[r]   = r0[0] + b_ih[r];
    ig1[r] = r1[0] + b_ih[r];
  }
}

// ---- fast transcendentals ----
__device__ __forceinline__ float fexp2_(float x){ return __builtin_amdgcn_exp2f(x); }
__device__ __forceinline__ float frcp_(float x){ return __builtin_amdgcn_rcpf(x); }
__device__ __forceinline__ float fsig_(float x){
  return frcp_(1.f + fexp2_(x * -1.44269504f));
}
__device__ __forceinline__ float ftanh_(float x){
  return 1.f - 2.f * frcp_(fexp2_(x * 2.88539008f) + 1.f);
}
__device__ __forceinline__ float dppx1_(float x){
  return __builtin_bit_cast(float,
      __builtin_amdgcn_mov_dpp(__builtin_bit_cast(int, x), 0xB1, 0xF, 0xF, true));
}

// Sequential recurrence — REVERTED to the R5 measured optimum (72us):
// 256 threads (4 waves, 1/SIMD), 2-way k-split pairs, 1 barrier/step,
// LDS h-history. R6's 512-thread/2-waves-per-SIMD variant regressed to 89us:
// barrier turnaround scales with waves-per-barrier; TLP does not help this
// per-step-synchronized loop.
__global__
__attribute__((amdgpu_flat_work_group_size(256, 256), amdgpu_waves_per_eu(1, 1)))
void k_recur(const float* __restrict__ P,
    const float* __restrict__ W_hh, const float* __restrict__ q,
    const float* __restrict__ b_n, const float* __restrict__ ig1,
    float* __restrict__ H_T)
{
  const int t = threadIdx.x;
  const int e = t >> 1;          // hidden element 0..127
  const int p = t & 1;           // k-half within the pair

  const float* rP0 = P    + (size_t)e         * HIDDEN + p*64;
  const float* rP1 = P    + (size_t)(128 + e) * HIDDEN + p*64;
  const float* rP2 = P    + (size_t)(256 + e) * HIDDEN + p*64;
  const float* rH0 = W_hh + (size_t)e         * HIDDEN + p*64;
  const float* rH1 = W_hh + (size_t)(128 + e) * HIDDEN + p*64;
  const float* rH2 = W_hh + (size_t)(256 + e) * HIDDEN + p*64;

  // q biases carried by the p=0 partials only (added once per full sum)
  const float qa = p ? 0.f : q[e];
  const float qb = p ? 0.f : q[128 + e];
  const float qc = p ? 0.f : q[256 + e];

  h2_t wP0[32], wP1[32], wP2[32], wH0[32], wH1[32], wH2[32];
#define LOADROW(DST, SRC)                                                     \
  { const float4* f = (const float4*)(SRC);                                   \
    _Pragma("unroll")                                                         \
    for (int j = 0; j < 16; j++){                                             \
      float4 v = f[j];                                                        \
      h2_t w;                                                                 \
      w.x=(half_t)v.x; w.y=(half_t)v.y; DST[2*j]   = w;                       \
      w.x=(half_t)v.z; w.y=(half_t)v.w; DST[2*j+1] = w;                       \
    } }
  LOADROW(wP0, rP0); LOADROW(wP1, rP1); LOADROW(wP2, rP2);
  LOADROW(wH0, rH0); LOADROW(wH1, rH1); LOADROW(wH2, rH2);
#undef LOADROW

  __shared__ __align__(16) half_t h16[2][HIDDEN];   // double-buffered broadcast
  __shared__ float Hs[128 * 101];                   // h history, padded rows

  const float bn = b_n[e];
  float h;
  {
    float reset = fsig_(ig1[e]);
    float inp   = fsig_(ig1[128 + e]);
    float nw    = ftanh_(ig1[256 + e] + reset * bn);
    h = nw - inp * nw;
  }
  if (!p) h16[0][e] = (half_t)h;
  else    Hs[e * 101] = h;
  __syncthreads();

  // step KK: reads own k-half of h16[RD], computes 6 half-dots, pair-sums via
  // DPP, nonlinearity redundantly in both lanes. One barrier.
#define RSTEP(KK, RD, WR)                                                     \
  {                                                                           \
    const uint4* hq = ((const uint4*)(h16[RD])) + p*8;                        \
    float a0 = qa,  a1 = 0.f;   /* P row e      -> ig_r partial */            \
    float b0 = qb,  b1 = 0.f;   /* P row 128+e  -> ig_i partial */            \
    float c0 = qc,  c1 = 0.f;   /* P row 256+e  -> ig_n partial */            \
    float d0 = 0.f, d1 = 0.f;   /* W row e      -> hg_r partial */            \
    float g0 = 0.f, g1 = 0.f;   /* W row 128+e  -> hg_i partial */            \
    float f0 = 0.f, f1 = 0.f;   /* W row 256+e  -> hg_n partial */            \
    _Pragma("unroll")                                                         \
    for (int jj = 0; jj < 8; jj++){                                           \
      uint4 hb = hq[jj];                                                      \
      h2_t hx = __builtin_bit_cast(h2_t, hb.x);                               \
      h2_t hy = __builtin_bit_cast(h2_t, hb.y);                               \
      h2_t hz = __builtin_bit_cast(h2_t, hb.z);                               \
      h2_t hw = __builtin_bit_cast(h2_t, hb.w);                               \
      a0 = __builtin_amdgcn_fdot2(wP0[4*jj+0], hx, a0, false);                \
      a1 = __builtin_amdgcn_fdot2(wP0[4*jj+1], hy, a1, false);                \
      a0 = __builtin_amdgcn_fdot2(wP0[4*jj+2], hz, a0, false);                \
      a1 = __builtin_amdgcn_fdot2(wP0[4*jj+3], hw, a1, false);                \
      b0 = __builtin_amdgcn_fdot2(wP1[4*jj+0], hx, b0, false);                \
      b1 = __builtin_amdgcn_fdot2(wP1[4*jj+1], hy, b1, false);                \
      b0 = __builtin_amdgcn_fdot2(wP1[4*jj+2], hz, b0, false);                \
      b1 = __builtin_amdgcn_fdot2(wP1[4*jj+3], hw, b1, false);                \
      c0 = __builtin_amdgcn_fdot2(wP2[4*jj+0], hx, c0, false);                \
      c1 = __builtin_amdgcn_fdot2(wP2[4*jj+1], hy, c1, false);                \
      c0 = __builtin_amdgcn_fdot2(wP2[4*jj+2], hz, c0, false);                \
      c1 = __builtin_amdgcn_fdot2(wP2[4*jj+3], hw, c1, false);                \
      d0 = __builtin_amdgcn_fdot2(wH0[4*jj+0], hx, d0, false);                \
      d1 = __builtin_amdgcn_fdot2(wH0[4*jj+1], hy, d1, false);                \
      d0 = __builtin_amdgcn_fdot2(wH0[4*jj+2], hz, d0, false);                \
      d1 = __builtin_amdgcn_fdot2(wH0[4*jj+3], hw, d1, false);                \
      g0 = __builtin_amdgcn_fdot2(wH1[4*jj+0], hx, g0, false);                \
      g1 = __builtin_amdgcn_fdot2(wH1[4*jj+1], hy, g1, false);                \
      g0 = __builtin_amdgcn_fdot2(wH1[4*jj+2], hz, g0, false);                \
      g1 = __builtin_amdgcn_fdot2(wH1[4*jj+3], hw, g1, false);                \
      f0 = __builtin_amdgcn_fdot2(wH2[4*jj+0], hx, f0, false);                \
      f1 = __builtin_amdgcn_fdot2(wH2[4*jj+1], hy, f1, false);                \
      f0 = __builtin_amdgcn_fdot2(wH2[4*jj+2], hz, f0, false);                \
      f1 = __builtin_amdgcn_fdot2(wH2[4*jj+3], hw, f1, false);                \
    }                                                                         \
    float A = a0 + a1, B = b0 + b1, C = c0 + c1;                              \
    float D = d0 + d1, G = g0 + g1, F = f0 + f1;                              \
    A += dppx1_(A); B += dppx1_(B); C += dppx1_(C);                           \
    D += dppx1_(D); G += dppx1_(G); F += dppx1_(F);                           \
    float rs = fsig_(A + D);                                                  \
    float ip = fsig_(B + G);                                                  \
    float nw = ftanh_(C + rs * (F + bn));                                     \
    h = nw + ip * (h - nw);                                                   \
    if (!p) h16[WR][e] = (half_t)h;                                           \
    else    Hs[e * 101 + (KK)] = h;                                           \
    __syncthreads();                                                          \
  }

  for (int k = 1; k < STEPS - 1; k += 2){
    RSTEP(k,     0, 1);
    RSTEP(k + 1, 1, 0);
  }
  RSTEP(STEPS - 1, 0, 1); // k = 99
#undef RSTEP

  // Coalesced dump: H_T[e*128 + k] = Hs[e][k] (k<100), 0 otherwise.
  for (int i = 0; i < 64; i++){
    int f = i * 256 + t;
    int ee = f >> 7, kk = f & 127;
    H_T[f] = (kk < STEPS) ? Hs[ee * 101 + kk] : 0.f;
  }
}

// X[k][d] = W_dec[d,:]@h_k + b_dec[d].
// R7 rewrite: wave-uniform H reads via the SCALAR path. Wave w owns k-steps
// [25w, 25w+25); lane owns one d-column. W_dec staged in LDS (contiguous
// coalesced load) at row stride 129 (129 mod 32 = 1 -> 64 lanes reading
// column j of distinct rows are conflict-free). Inner loop per j: one
// ds_read_b32 (own W element) + 25 fmac with H[j][k0+k], whose address is
// wave-uniform (k0 forced via readfirstlane) -> compiler scalarizes to merged
// s_loads: H is read once per block (51KB) instead of 1MB/block through VMEM.
// Old version's 800MB of L2 H-traffic (~24us device-wide) disappears; kernel
// becomes VALU-bound (~11us) + stores.
__global__ __launch_bounds__(256, 4) void k_decode(const float* __restrict__ W_dec,
    const float* __restrict__ b_dec, const float* __restrict__ H_T,
    float* __restrict__ out)
{
  __shared__ float Ws[64 * 129];   // 33024 B
  const int t    = threadIdx.x;
  const int lane = t & 63;
  const int wv   = __builtin_amdgcn_readfirstlane(t >> 6);  // wave id 0..3
  const int d0   = blockIdx.x * 64;
  const int d    = d0 + lane;

  // Stage: 64 rows x 128 floats = one contiguous 32KB span of W_dec.
  // Scalar LDS writes (stride-129 rows are not float4-aligned); one-time cost.
  #pragma unroll
  for (int i = 0; i < 8; i++){
    int f4 = i * 256 + t;          // 0..2047 float4s
    int rl = f4 >> 5;              // local row 0..63
    int cl = (f4 & 31) * 4;        // col 0,4,..,124
    int rg = d0 + rl;
    float4 v = *(const float4*)&W_dec[(size_t)((rg < IDIM) ? rg : (IDIM-1))*HIDDEN + cl];
    Ws[rl*129 + cl + 0] = v.x;
    Ws[rl*129 + cl + 1] = v.y;
    Ws[rl*129 + cl + 2] = v.z;
    Ws[rl*129 + cl + 3] = v.w;
  }
  __syncthreads();

  const int k0 = wv * 25;          // this wave's k-range [k0, k0+25)
  float acc[25];
  #pragma unroll
  for (int k = 0; k < 25; k++) acc[k] = 0.f;

  const float* wrow = &Ws[lane * 129];
  #pragma unroll 2
  for (int j = 0; j < HIDDEN; j++){
    float w = wrow[j];                               // ds_read_b32, conflict-free
    const float* hp = &H_T[j * HIDDEN + k0];         // wave-uniform address
    #pragma unroll
    for (int k = 0; k < 25; k++)
      acc[k] = fmaf(w, hp[k], acc[k]);               // v_fmac with SGPR operand
  }

  if (d < IDIM){
    const float bd = b_dec[d];
    const size_t SO = (size_t)STEPS * IDIM;  // 5,000,000
    #pragma unroll
    for (int k = 0; k < 25; k++){
      float v = acc[k] + bd;
      size_t o = (size_t)(k0 + k) * IDIM + d;        // 64 lanes -> 256B contiguous
      out[o]        = v;     // samples
      out[o + SO]   = v;     // means
      out[o + 2*SO] = 0.f;   // sigmas
    }
  }
}

extern "C" void kernel_launch(void* const* d_in, const int* in_sizes, int n_in,
                              void* d_out, int out_size, void* d_ws, size_t ws_size,
                              hipStream_t stream) {
  const float* x0    = (const float*)d_in[0];
  const float* W_enc = (const float*)d_in[1];
  const float* b_enc = (const float*)d_in[2];
  const float* W_ih  = (const float*)d_in[3];
  const float* W_hh  = (const float*)d_in[4];
  const float* b_ih  = (const float*)d_in[5];
  const float* b_n   = (const float*)d_in[6];
  const float* W_dec = (const float*)d_in[7];
  const float* b_dec = (const float*)d_in[8];
  (void)in_sizes; (void)n_in; (void)out_size; (void)ws_size;

  float* out = (float*)d_out;
  float* ws  = (float*)d_ws;
  float* M   = ws + WS_M;
  float* P   = ws + WS_P;
  float* q   = ws + WS_Q;
  float* ig1 = ws + WS_IG1;
  float* H_T = ws + WS_HT;
  float* scratch = out + SC_PART;  // 32 MB of d_out, dead until k_decode
  float* Mp      = out + SC_MP;    // 640 KB of d_out, ditto

  hipLaunchKernelGGL(k_encgemm, dim3(756), dim3(256), 0, stream, W_enc, W_dec, x0, b_dec, ws, scratch);
  hipLaunchKernelGGL(k_reduce1, dim3(640), dim3(256), 0, stream, scratch, Mp);
  hipLaunchKernelGGL(k_reduce2, dim3(64),  dim3(256), 0, stream, Mp, M);
  hipLaunchKernelGGL(k_smallP,  dim3(384), dim3(128), 0, stream, W_ih, b_ih, b_enc, ws, M, P, q, ig1);
  hipLaunchKernelGGL(k_recur,   dim3(1),   dim3(256), 0, stream, P, W_hh, q, b_n, ig1, H_T);
  hipLaunchKernelGGL(k_decode,  dim3(782), dim3(256), 0, stream, W_dec, b_dec, H_T, out);
}